// Round 7
// baseline (204.390 us; speedup 1.0000x reference)
//
#include <hip/hip_runtime.h>

#define NCLS 10
#define TPB  256
#define NBLK 2048
#define ACC_STRIDE 64   // floats between global accumulator slots (256 B)

typedef float vfloat4 __attribute__((ext_vector_type(4)));
typedef int   vint4   __attribute__((ext_vector_type(4)));

// ws: slot j in [0,20): j<10 class sqerr sum, j>=10 class count. ws[j*ACC_STRIDE].

__device__ __forceinline__ void proc_elem(float o, float t, int m,
                                          float sum[NCLS], unsigned long long &cnt)
{
    float d  = o - t;
    float sq = d * d;
    int cls  = (m == 1) ? (int)t : NCLS;     // 10 = dummy
    cnt += 1ull << (6 * cls);                // 10x 6-bit counters; dummy spills off the top
#pragma unroll
    for (int c = 0; c < NCLS; ++c)
        sum[c] += (cls == c) ? sq : 0.0f;    // v_cmp + v_cndmask + v_add
}

__device__ __forceinline__ void proc_group(const vfloat4 &o, const vfloat4 &t,
                                           const vint4 &m,
                                           float sum[NCLS], unsigned long long &cnt)
{
    proc_elem(o.x, t.x, m.x, sum, cnt);
    proc_elem(o.y, t.y, m.y, sum, cnt);
    proc_elem(o.z, t.z, m.z, sum, cnt);
    proc_elem(o.w, t.w, m.w, sum, cnt);
}

// async global->LDS DMA, 16 B per lane. LDS dest = wave-uniform base + lane*16.
__device__ __forceinline__ void dma16(const void* g, void* l)
{
    __builtin_amdgcn_global_load_lds(
        (const __attribute__((address_space(1))) void*)g,
        (__attribute__((address_space(3))) void*)l,
        16, 0, 0);
}

__global__ __launch_bounds__(TPB) void loss_main_kernel(
    const float* __restrict__ outputs,
    const float* __restrict__ targets,
    const int*   __restrict__ mask,
    float* __restrict__ ws,
    int n4, int n_rem_base, int n_rem)
{
    // chunk = 256 float4-groups: 4 KB per stream per buffer. 24 KB total dbuf.
    __shared__ float ldsO[2][TPB * 4];
    __shared__ float ldsT[2][TPB * 4];
    __shared__ int   ldsM[2][TPB * 4];

    const vfloat4* o4 = (const vfloat4*)outputs;
    const vfloat4* t4 = (const vfloat4*)targets;
    const vint4*   m4 = (const vint4*)mask;

    const int tx = threadIdx.x;
    const int w  = tx >> 6;          // wave id in block
    const int G  = NBLK;             // grid size

    float sum[NCLS];
#pragma unroll
    for (int c = 0; c < NCLS; ++c) sum[c] = 0.0f;
    unsigned long long cnt = 0;

    const int nch = n4 >> 8;         // chunks of 256 groups (16384 for benchmark)

    int c = blockIdx.x;
    if (c < nch) {
        // prefetch chunk c into buffer 0 (3 DMAs per wave, no VGPR dest)
        dma16(&o4[c * TPB + tx], &ldsO[0][w << 8]);
        dma16(&t4[c * TPB + tx], &ldsT[0][w << 8]);
        dma16(&m4[c * TPB + tx], &ldsM[0][w << 8]);
    }

    int it = 0;
    for (; c < nch; c += G, ++it) {
        const int buf = it & 1;
        __syncthreads();             // vmcnt drain: buf's chunk is resident
        const int cn = c + G;
        if (cn < nch) {              // prefetch next chunk into other buffer
            dma16(&o4[cn * TPB + tx], &ldsO[buf ^ 1][w << 8]);
            dma16(&t4[cn * TPB + tx], &ldsT[buf ^ 1][w << 8]);
            dma16(&m4[cn * TPB + tx], &ldsM[buf ^ 1][w << 8]);
        }
        vfloat4 o = *(const vfloat4*)&ldsO[buf][tx * 4];
        vfloat4 t = *(const vfloat4*)&ldsT[buf][tx * 4];
        vint4   m = *(const vint4*)  &ldsM[buf][tx * 4];
        proc_group(o, t, m, sum, cnt);
    }

    // leftover whole groups (n4 % 256 per-chunk remainder); empty for benchmark
    for (int i = nch * TPB + blockIdx.x * TPB + tx; i < n4; i += G * TPB) {
        vfloat4 o = __builtin_nontemporal_load(&o4[i]);
        vfloat4 t = __builtin_nontemporal_load(&t4[i]);
        vint4   m = __builtin_nontemporal_load(&m4[i]);
        proc_group(o, t, m, sum, cnt);
    }
    // scalar tail (n % 4); empty for benchmark
    int gtid = blockIdx.x * TPB + tx;
    if (gtid < n_rem)
        proc_elem(outputs[n_rem_base + gtid], targets[n_rem_base + gtid],
                  mask[n_rem_base + gtid], sum, cnt);

    // unpack packed counters to floats
    float cfl[NCLS];
#pragma unroll
    for (int c2 = 0; c2 < NCLS; ++c2)
        cfl[c2] = (float)((unsigned)(cnt >> (6 * c2)) & 63u);

    // wave reduction
#pragma unroll
    for (int c2 = 0; c2 < NCLS; ++c2) {
#pragma unroll
        for (int off = 32; off > 0; off >>= 1) {
            sum[c2] += __shfl_down(sum[c2], off, 64);
            cfl[c2] += __shfl_down(cfl[c2], off, 64);
        }
    }

    // cross-wave reduction + 20 global atomics per block
    __shared__ float lsS[4][NCLS];
    __shared__ float lsC[4][NCLS];
    int lane = tx & 63;
    if (lane == 0) {
#pragma unroll
        for (int c2 = 0; c2 < NCLS; ++c2) {
            lsS[w][c2] = sum[c2];
            lsC[w][c2] = cfl[c2];
        }
    }
    __syncthreads();

    if (tx < 2 * NCLS) {
        int c2 = (tx < NCLS) ? tx : (tx - NCLS);
        float v;
        if (tx < NCLS)
            v = lsS[0][c2] + lsS[1][c2] + lsS[2][c2] + lsS[3][c2];
        else
            v = lsC[0][c2] + lsC[1][c2] + lsC[2][c2] + lsC[3][c2];
        atomicAdd(&ws[tx * ACC_STRIDE], v);
    }
}

__global__ __launch_bounds__(64) void loss_final_kernel(
    const float* __restrict__ ws,
    float* __restrict__ out)
{
    int lane = threadIdx.x;   // single wave
    float le = 0.0f;
    if (lane < NCLS) {
        float s  = ws[lane * ACC_STRIDE];
        float cn = ws[(NCLS + lane) * ACC_STRIDE];
        le = (cn > 0.0f) ? (s / fmaxf(cn, 1.0f)) : 0.0f;
        out[1 + lane]  = le;        // loss_each
        out[11 + lane] = cn;        // class_n
    }
    float wsum = 0.1f * le;         // WEIGHT = 0.1 per class
#pragma unroll
    for (int off = 32; off > 0; off >>= 1) wsum += __shfl_down(wsum, off, 64);
    if (lane == 0) out[0] = wsum;   // loss
}

extern "C" void kernel_launch(void* const* d_in, const int* in_sizes, int n_in,
                              void* d_out, int out_size, void* d_ws, size_t ws_size,
                              hipStream_t stream)
{
    const float* outputs = (const float*)d_in[0];
    const float* targets = (const float*)d_in[1];
    const int*   mask    = (const int*)d_in[2];
    float* out = (float*)d_out;
    float* ws  = (float*)d_ws;

    int n  = in_sizes[0];
    int n4 = n / 4;
    int n_rem_base = 4 * n4;
    int n_rem = n - n_rem_base;

    hipMemsetAsync(d_ws, 0, 2 * NCLS * ACC_STRIDE * sizeof(float), stream);
    loss_main_kernel<<<NBLK, TPB, 0, stream>>>(outputs, targets, mask, ws,
                                               n4, n_rem_base, n_rem);
    loss_final_kernel<<<1, 64, 0, stream>>>(ws, out);
}

// Round 8
// 191.551 us; speedup vs baseline: 1.0670x; 1.0670x over previous
//
#include <hip/hip_runtime.h>

#define NCLS 10
#define TPB  256
#define NBLK 2048
#define ACC_STRIDE 64   // floats between global accumulator slots (256 B)

typedef float  vfloat4 __attribute__((ext_vector_type(4)));
typedef int    vint4   __attribute__((ext_vector_type(4)));
typedef float  vfloat2 __attribute__((ext_vector_type(2)));

// ws: slot j in [0,20): j<10 class sqerr sum, j>=10 class count. ws[j*ACC_STRIDE].

// --- inline-asm loads: sc0 = L1-bypass (L2-coherent read), nt = no-allocate.
// asm volatile can't be sunk by the scheduler (R5/R6: compiler defeats deep
// source-level pipelines); vmcnt is controlled manually below.
__device__ __forceinline__ void ld16f(vfloat4 &d, const vfloat4 *p) {
    asm volatile("global_load_dwordx4 %0, %1, off sc0 nt"
                 : "=v"(d) : "v"(p) : "memory");
}
__device__ __forceinline__ void ld16i(vint4 &d, const vint4 *p) {
    asm volatile("global_load_dwordx4 %0, %1, off sc0 nt"
                 : "=v"(d) : "v"(p) : "memory");
}
// waitcnt pinned to the regs it guards ("+v") so uses can't be scheduled above it
__device__ __forceinline__ void wait3(vfloat4 &o, vfloat4 &t, vint4 &m) {
    asm volatile("s_waitcnt vmcnt(3)" : "+v"(o), "+v"(t), "+v"(m) :: "memory");
}
__device__ __forceinline__ void wait0(vfloat4 &o, vfloat4 &t, vint4 &m) {
    asm volatile("s_waitcnt vmcnt(0)" : "+v"(o), "+v"(t), "+v"(m) :: "memory");
}

__device__ __forceinline__ void proc_elem(float o, float t, int m,
                                          vfloat2 s2[5], unsigned long long &cnt)
{
    float d  = o - t;
    float sq = d * d;
    int cls  = (m == 1) ? (int)t : NCLS;     // 10 = dummy
    cnt += 1ull << (6 * cls);                // 10x 6-bit counters; dummy spills off the top
    int b = cls & 1;
    int h = cls >> 1;                        // 0..4 real, 5 = dummy-high
    vfloat2 se;
    se.x = (b == 0) ? sq : 0.0f;
    se.y = (b == 0) ? 0.0f : sq;
#pragma unroll
    for (int p = 0; p < 5; ++p) {
        vfloat2 z = {0.0f, 0.0f};
        vfloat2 inc = (h == p) ? se : z;     // cmp + 2 cndmask
        s2[p] += inc;                        // v_pk_add_f32
    }
}

__device__ __forceinline__ void proc_group(const vfloat4 &o, const vfloat4 &t,
                                           const vint4 &m,
                                           vfloat2 s2[5], unsigned long long &cnt)
{
    proc_elem(o.x, t.x, m.x, s2, cnt);
    proc_elem(o.y, t.y, m.y, s2, cnt);
    proc_elem(o.z, t.z, m.z, s2, cnt);
    proc_elem(o.w, t.w, m.w, s2, cnt);
}

__global__ __launch_bounds__(TPB) void loss_main_kernel(
    const float* __restrict__ outputs,
    const float* __restrict__ targets,
    const int*   __restrict__ mask,
    float* __restrict__ ws,
    int n4, int n_rem_base, int n_rem)
{
    const vfloat4* o4 = (const vfloat4*)outputs;
    const vfloat4* t4 = (const vfloat4*)targets;
    const vint4*   m4 = (const vint4*)mask;

    const int tid = blockIdx.x * TPB + threadIdx.x;
    const int T   = NBLK * TPB;

    vfloat2 s2[5];
#pragma unroll
    for (int p = 0; p < 5; ++p) { s2[p].x = 0.0f; s2[p].y = 0.0f; }
    unsigned long long cnt = 0;

    if (n4 == 8 * T) {
        // Benchmark shape: 8 float4-groups/thread. A = even groups, B = odd.
        // Steady state: 6 loads outstanding, waits never drain below vmcnt(3)
        // until the final group (hipBLASLt-style fine-grained pipeline).
        vfloat4 oA, tA, oB, tB;
        vint4   mA, mB;
        ld16f(oA, &o4[tid + 0 * T]); ld16f(tA, &t4[tid + 0 * T]); ld16i(mA, &m4[tid + 0 * T]);
        ld16f(oB, &o4[tid + 1 * T]); ld16f(tB, &t4[tid + 1 * T]); ld16i(mB, &m4[tid + 1 * T]);

#pragma unroll
        for (int j = 0; j < 3; ++j) {
            wait3(oA, tA, mA);                 // A_j ready; B_j still in flight
            vfloat4 o = oA, t = tA; vint4 m = mA;   // renamed, zero-cost
            ld16f(oA, &o4[tid + (2 * j + 2) * T]);
            ld16f(tA, &t4[tid + (2 * j + 2) * T]);
            ld16i(mA, &m4[tid + (2 * j + 2) * T]);
            proc_group(o, t, m, s2, cnt);

            wait3(oB, tB, mB);                 // B_j ready; A_{j+1} in flight
            vfloat4 o2 = oB, t2 = tB; vint4 m2 = mB;
            ld16f(oB, &o4[tid + (2 * j + 3) * T]);
            ld16f(tB, &t4[tid + (2 * j + 3) * T]);
            ld16i(mB, &m4[tid + (2 * j + 3) * T]);
            proc_group(o2, t2, m2, s2, cnt);
        }
        wait3(oA, tA, mA);
        proc_group(oA, tA, mA, s2, cnt);
        wait0(oB, tB, mB);
        proc_group(oB, tB, mB, s2, cnt);
    } else {
        // generic fallback for any size (compiler-scheduled A/B)
        const int full  = n4 / T;
        const int kfull = full & ~1;
        if (kfull >= 2) {
            vfloat4 oA, tA, oB, tB;
            vint4   mA, mB;
            oA = __builtin_nontemporal_load(&o4[tid]);
            tA = __builtin_nontemporal_load(&t4[tid]);
            mA = __builtin_nontemporal_load(&m4[tid]);
            oB = __builtin_nontemporal_load(&o4[tid + T]);
            tB = __builtin_nontemporal_load(&t4[tid + T]);
            mB = __builtin_nontemporal_load(&m4[tid + T]);
            int k = 0;
            while (true) {
                proc_group(oA, tA, mA, s2, cnt);
                if (k + 2 < kfull) {
                    int i = tid + (k + 2) * T;
                    oA = __builtin_nontemporal_load(&o4[i]);
                    tA = __builtin_nontemporal_load(&t4[i]);
                    mA = __builtin_nontemporal_load(&m4[i]);
                }
                proc_group(oB, tB, mB, s2, cnt);
                if (k + 3 < kfull) {
                    int i = tid + (k + 3) * T;
                    oB = __builtin_nontemporal_load(&o4[i]);
                    tB = __builtin_nontemporal_load(&t4[i]);
                    mB = __builtin_nontemporal_load(&m4[i]);
                }
                k += 2;
                if (k >= kfull) break;
            }
        }
        for (int i = tid + kfull * T; i < n4; i += T) {
            vfloat4 o = __builtin_nontemporal_load(&o4[i]);
            vfloat4 t = __builtin_nontemporal_load(&t4[i]);
            vint4   m = __builtin_nontemporal_load(&m4[i]);
            proc_group(o, t, m, s2, cnt);
        }
    }
    // scalar tail (n % 4); empty for the benchmark
    if (tid < n_rem)
        proc_elem(outputs[n_rem_base + tid], targets[n_rem_base + tid],
                  mask[n_rem_base + tid], s2, cnt);

    // unpack: s2[p] = {class 2p, class 2p+1}; counts from packed u64
    float sum[NCLS], cfl[NCLS];
#pragma unroll
    for (int p = 0; p < 5; ++p) {
        sum[2 * p]     = s2[p].x;
        sum[2 * p + 1] = s2[p].y;
    }
#pragma unroll
    for (int c = 0; c < NCLS; ++c)
        cfl[c] = (float)((unsigned)(cnt >> (6 * c)) & 63u);

    // wave reduction
#pragma unroll
    for (int c = 0; c < NCLS; ++c) {
#pragma unroll
        for (int off = 32; off > 0; off >>= 1) {
            sum[c] += __shfl_down(sum[c], off, 64);
            cfl[c] += __shfl_down(cfl[c], off, 64);
        }
    }

    // cross-wave reduction + 20 global atomics per block
    __shared__ float lsS[4][NCLS];
    __shared__ float lsC[4][NCLS];
    int wave = threadIdx.x >> 6;
    int lane = threadIdx.x & 63;
    if (lane == 0) {
#pragma unroll
        for (int c = 0; c < NCLS; ++c) {
            lsS[wave][c] = sum[c];
            lsC[wave][c] = cfl[c];
        }
    }
    __syncthreads();

    if (threadIdx.x < 2 * NCLS) {
        int c = (threadIdx.x < NCLS) ? threadIdx.x : (threadIdx.x - NCLS);
        float v;
        if (threadIdx.x < NCLS)
            v = lsS[0][c] + lsS[1][c] + lsS[2][c] + lsS[3][c];
        else
            v = lsC[0][c] + lsC[1][c] + lsC[2][c] + lsC[3][c];
        atomicAdd(&ws[threadIdx.x * ACC_STRIDE], v);
    }
}

__global__ __launch_bounds__(64) void loss_final_kernel(
    const float* __restrict__ ws,
    float* __restrict__ out)
{
    int lane = threadIdx.x;   // single wave
    float le = 0.0f;
    if (lane < NCLS) {
        float s  = ws[lane * ACC_STRIDE];
        float cn = ws[(NCLS + lane) * ACC_STRIDE];
        le = (cn > 0.0f) ? (s / fmaxf(cn, 1.0f)) : 0.0f;
        out[1 + lane]  = le;        // loss_each
        out[11 + lane] = cn;        // class_n
    }
    float w = 0.1f * le;            // WEIGHT = 0.1 per class
#pragma unroll
    for (int off = 32; off > 0; off >>= 1) w += __shfl_down(w, off, 64);
    if (lane == 0) out[0] = w;      // loss
}

extern "C" void kernel_launch(void* const* d_in, const int* in_sizes, int n_in,
                              void* d_out, int out_size, void* d_ws, size_t ws_size,
                              hipStream_t stream)
{
    const float* outputs = (const float*)d_in[0];
    const float* targets = (const float*)d_in[1];
    const int*   mask    = (const int*)d_in[2];
    float* out = (float*)d_out;
    float* ws  = (float*)d_ws;

    int n  = in_sizes[0];
    int n4 = n / 4;
    int n_rem_base = 4 * n4;
    int n_rem = n - n_rem_base;

    hipMemsetAsync(d_ws, 0, 2 * NCLS * ACC_STRIDE * sizeof(float), stream);
    loss_main_kernel<<<NBLK, TPB, 0, stream>>>(outputs, targets, mask, ws,
                                               n4, n_rem_base, n_rem);
    loss_final_kernel<<<1, 64, 0, stream>>>(ws, out);
}